// Round 5
// baseline (476.507 us; speedup 1.0000x reference)
//
#include <hip/hip_runtime.h>
#include <math.h>

#define NQ    12
#define DIM   4096        // 2^NQ
#define NSAMP 2048
#define NLAY  3
#define NT    32          // 2048/64 tiles per dimension
#define NTRI  528         // NT*(NT+1)/2 triangular blocks
#define BK    64
#define LDK   70          // LDS row stride (ushort): 140 B = 35 banks, gcd(35,32)=1 -> 2-way reads (free)

typedef __attribute__((ext_vector_type(8)))  short bf16x8;   // 8 bf16 = 4 VGPRs
typedef __attribute__((ext_vector_type(16))) float floatx16; // MFMA 32x32 acc

__device__ __forceinline__ unsigned short f32_to_bf16(float x) {
    unsigned u = __builtin_bit_cast(unsigned, x);
    u += 0x7FFFu + ((u >> 16) & 1u);            // round-to-nearest-even
    return (unsigned short)(u >> 16);
}
__device__ __forceinline__ float bf16_to_f32(unsigned short h) {
    unsigned u = (unsigned)h << 16;
    return __builtin_bit_cast(float, u);
}

// ---------------------------------------------------------------------------
// Kernel 1: 12-qubit circuit per sample, state in LDS.  Emits psi = hi + lo
// as two bf16 arrays.  Qubit->bit mapping is a fixed global permutation:
// inner products invariant, CZ ring edge set maps to itself.
// ---------------------------------------------------------------------------
__global__ __launch_bounds__(256) void sim_kernel(const float* __restrict__ data,
                                                  const float* __restrict__ params,
                                                  unsigned short* __restrict__ psi_hi,
                                                  unsigned short* __restrict__ psi_lo)
{
    __shared__ float st[DIM];
    __shared__ float cs[NLAY*NQ], sn[NLAY*NQ];
    const int tid = threadIdx.x;
    const int smp = blockIdx.x;

    if (tid < NLAY*NQ) {
        const int q = tid % NQ;
        const float th = 0.5f * (params[tid] + data[smp*NQ + q]);
        cs[tid] = cosf(th);
        sn[tid] = sinf(th);
    }
    #pragma unroll
    for (int u = 0; u < DIM/256; ++u) st[tid + u*256] = 0.0f;
    if (tid == 0) st[0] = 1.0f;
    __syncthreads();

    for (int l = 0; l < NLAY; ++l) {
        for (int q = 0; q < NQ; ++q) {
            const float c = cs[l*NQ + q], s = sn[l*NQ + q];
            const int m = 1 << q;
            #pragma unroll
            for (int u = 0; u < DIM/2/256; ++u) {
                const int p  = tid + u*256;
                const int i0 = ((p & ~(m-1)) << 1) | (p & (m-1));
                const int i1 = i0 | m;
                const float a0 = st[i0], a1 = st[i1];
                st[i0] = c*a0 - s*a1;
                st[i1] = s*a0 + c*a1;
            }
            __syncthreads();
        }
        #pragma unroll
        for (int u = 0; u < DIM/256; ++u) {
            const int i = tid + u*256;
            const int y = (i >> 1) | ((i & 1) << (NQ-1));
            if (__popc(i & y) & 1) st[i] = -st[i];
        }
        __syncthreads();
    }
    // paired stores: 2 elems/thread/iter -> ushort2 (coalesced 4 B/lane)
    #pragma unroll
    for (int u = 0; u < DIM/512; ++u) {
        const int p = tid + u*256;     // pair index
        const int i = p*2;
        const float x0 = st[i], x1 = st[i+1];
        const unsigned short h0 = f32_to_bf16(x0);
        const unsigned short h1 = f32_to_bf16(x1);
        const unsigned short l0 = f32_to_bf16(x0 - bf16_to_f32(h0));
        const unsigned short l1 = f32_to_bf16(x1 - bf16_to_f32(h1));
        ushort2 vh; vh.x = h0; vh.y = h1;
        ushort2 vl; vl.x = l0; vl.y = l1;
        *(ushort2*)&psi_hi[(size_t)smp*DIM + i] = vh;
        *(ushort2*)&psi_lo[(size_t)smp*DIM + i] = vl;
    }
}

// ---------------------------------------------------------------------------
// Kernel 2: MFMA split-bf16 Gram + fused reduction.  Compact triangular grid
// of 528 blocks; block -> (bi,bj), bj>=bi.  64x64 tile of
// G = hi.hi^T + hi.lo^T + lo.hi^T.  K-split: each of 4 waves computes the
// full 64x64 tile (2x2 frags of mfma_f32_32x32x16_bf16) over its own 16-k
// slice; partials summed in LDS (aliased over staging) before squaring.
// Element weight 2/1/0 handles symmetry.
// ---------------------------------------------------------------------------
__global__ __launch_bounds__(256, 2) void gram_kernel(const unsigned short* __restrict__ ph,
                                                      const unsigned short* __restrict__ pl,
                                                      const int* __restrict__ labels,
                                                      double* __restrict__ part1,
                                                      double* __restrict__ part2)
{
    __shared__ __align__(16) unsigned short stage[4*64*LDK];
    __shared__ float la[64], lb[64];

    unsigned short* Ah = stage;
    unsigned short* Al = stage + 64*LDK;
    unsigned short* Bh = stage + 2*64*LDK;
    unsigned short* Bl = stage + 3*64*LDK;
    float*  Gt  = (float*)stage;       // alias: live after main loop (64 x 66)
    double* red = (double*)stage;      // alias: live after Gt reads complete

    const int tid = threadIdx.x;
    const int bid = blockIdx.x;

    // triangular index -> (bi,bj)
    int bi = (int)((65.0 - sqrt(65.0*65.0 - 8.0*(double)bid)) * 0.5);
    int start = bi*(65-bi)/2;
    while (bid < start)              { --bi; start = bi*(65-bi)/2; }
    while (bid >= start + (NT - bi)) { start += NT - bi; ++bi; }
    const int bj = bi + (bid - start);

    if (tid < 64)       la[tid]      = 2.0f*(float)labels[bi*64 + tid]      - 1.0f;
    else if (tid < 128) lb[tid - 64] = 2.0f*(float)labels[bj*64 + tid - 64] - 1.0f;

    const int wave = tid >> 6, lane = tid & 63;
    const int mrow = lane & 31;
    const int kgrp = (lane >> 5) * 8;   // A/B layout: lane holds M[lane&31][(lane>>5)*8 + j]
    const int kw   = wave * 16;         // this wave's k-slice within the BK=64 stage

    floatx16 acc00, acc01, acc10, acc11;
    #pragma unroll
    for (int i = 0; i < 16; ++i) { acc00[i]=0.f; acc01[i]=0.f; acc10[i]=0.f; acc11[i]=0.f; }

    // staging map: thread -> row sr (0..63), chunks sc and sc+32 (8 bf16 each)
    const int sr = tid >> 2;
    const int sc = (tid & 3) * 8;
    const size_t ga = ((size_t)bi*64 + sr) * DIM;
    const size_t gb = ((size_t)bj*64 + sr) * DIM;

    for (int kk = 0; kk < DIM; kk += BK) {
        const uint4 vah0 = *(const uint4*)(ph + ga + kk + sc);
        const uint4 vah1 = *(const uint4*)(ph + ga + kk + sc + 32);
        const uint4 val0 = *(const uint4*)(pl + ga + kk + sc);
        const uint4 val1 = *(const uint4*)(pl + ga + kk + sc + 32);
        const uint4 vbh0 = *(const uint4*)(ph + gb + kk + sc);
        const uint4 vbh1 = *(const uint4*)(ph + gb + kk + sc + 32);
        const uint4 vbl0 = *(const uint4*)(pl + gb + kk + sc);
        const uint4 vbl1 = *(const uint4*)(pl + gb + kk + sc + 32);
        __syncthreads();   // previous iter's LDS reads complete
        *(uint4*)&Ah[sr*LDK + sc]      = vah0;
        *(uint4*)&Ah[sr*LDK + sc + 32] = vah1;
        *(uint4*)&Al[sr*LDK + sc]      = val0;
        *(uint4*)&Al[sr*LDK + sc + 32] = val1;
        *(uint4*)&Bh[sr*LDK + sc]      = vbh0;
        *(uint4*)&Bh[sr*LDK + sc + 32] = vbh1;
        *(uint4*)&Bl[sr*LDK + sc]      = vbl0;
        *(uint4*)&Bl[sr*LDK + sc + 32] = vbl1;
        __syncthreads();

        const int ro = kw + kgrp;
        const bf16x8 ah0 = *(const bf16x8*)&Ah[(mrow     )*LDK + ro];
        const bf16x8 ah1 = *(const bf16x8*)&Ah[(mrow + 32)*LDK + ro];
        const bf16x8 al0 = *(const bf16x8*)&Al[(mrow     )*LDK + ro];
        const bf16x8 al1 = *(const bf16x8*)&Al[(mrow + 32)*LDK + ro];
        const bf16x8 bh0 = *(const bf16x8*)&Bh[(mrow     )*LDK + ro];
        const bf16x8 bh1 = *(const bf16x8*)&Bh[(mrow + 32)*LDK + ro];
        const bf16x8 bl0 = *(const bf16x8*)&Bl[(mrow     )*LDK + ro];
        const bf16x8 bl1 = *(const bf16x8*)&Bl[(mrow + 32)*LDK + ro];

        acc00 = __builtin_amdgcn_mfma_f32_32x32x16_bf16(ah0, bh0, acc00, 0, 0, 0);
        acc01 = __builtin_amdgcn_mfma_f32_32x32x16_bf16(ah0, bh1, acc01, 0, 0, 0);
        acc10 = __builtin_amdgcn_mfma_f32_32x32x16_bf16(ah1, bh0, acc10, 0, 0, 0);
        acc11 = __builtin_amdgcn_mfma_f32_32x32x16_bf16(ah1, bh1, acc11, 0, 0, 0);

        acc00 = __builtin_amdgcn_mfma_f32_32x32x16_bf16(ah0, bl0, acc00, 0, 0, 0);
        acc01 = __builtin_amdgcn_mfma_f32_32x32x16_bf16(ah0, bl1, acc01, 0, 0, 0);
        acc10 = __builtin_amdgcn_mfma_f32_32x32x16_bf16(ah1, bl0, acc10, 0, 0, 0);
        acc11 = __builtin_amdgcn_mfma_f32_32x32x16_bf16(ah1, bl1, acc11, 0, 0, 0);

        acc00 = __builtin_amdgcn_mfma_f32_32x32x16_bf16(al0, bh0, acc00, 0, 0, 0);
        acc01 = __builtin_amdgcn_mfma_f32_32x32x16_bf16(al0, bh1, acc01, 0, 0, 0);
        acc10 = __builtin_amdgcn_mfma_f32_32x32x16_bf16(al1, bh0, acc10, 0, 0, 0);
        acc11 = __builtin_amdgcn_mfma_f32_32x32x16_bf16(al1, bh1, acc11, 0, 0, 0);
    }

    __syncthreads();   // all staging reads done; stage memory reusable as Gt

    // Sum the 4 wave K-partials into Gt.  C/D layout (m74/m101):
    // row_local = (reg&3) + 8*(reg>>2) + 4*(lane>>5), col_local = lane&31.
    const int crow = (lane >> 5) * 4;
    const int ccol = lane & 31;
    for (int w = 0; w < 4; ++w) {
        if (wave == w) {
            #pragma unroll
            for (int r = 0; r < 16; ++r) {
                const int rl = (r & 3) + 8*(r >> 2) + crow;
                if (w == 0) {
                    Gt[(rl     )*66 + ccol     ] = acc00[r];
                    Gt[(rl     )*66 + ccol + 32] = acc01[r];
                    Gt[(rl + 32)*66 + ccol     ] = acc10[r];
                    Gt[(rl + 32)*66 + ccol + 32] = acc11[r];
                } else {
                    Gt[(rl     )*66 + ccol     ] += acc00[r];
                    Gt[(rl     )*66 + ccol + 32] += acc01[r];
                    Gt[(rl + 32)*66 + ccol     ] += acc10[r];
                    Gt[(rl + 32)*66 + ccol + 32] += acc11[r];
                }
            }
        }
        __syncthreads();
    }

    // Reduce: s1 += w*l_i*l_j*G^2, s2 += w*G^4 (w = 2 above diag, 1 on, 0 below)
    double s1 = 0.0, s2 = 0.0;
    #pragma unroll
    for (int u = 0; u < 16; ++u) {
        const int e   = u*256 + tid;
        const int row = e >> 6, col = e & 63;
        const float g = Gt[row*66 + col];
        const float w = (bi < bj) ? 2.0f : ((row < col) ? 2.0f : ((row == col) ? 1.0f : 0.0f));
        const float g2 = g * g;
        s1 += (double)(w * la[row] * lb[col] * g2);
        const double d = (double)g2;
        s2 += (double)w * d * d;
    }
    __syncthreads();   // Gt reads done before red alias is written

    red[tid] = s1; __syncthreads();
    for (int off = 128; off; off >>= 1) { if (tid < off) red[tid] += red[tid+off]; __syncthreads(); }
    if (tid == 0) part1[bid] = red[0];
    __syncthreads();
    red[tid] = s2; __syncthreads();
    for (int off = 128; off; off >>= 1) { if (tid < off) red[tid] += red[tid+off]; __syncthreads(); }
    if (tid == 0) part2[bid] = red[0];
}

// ---------------------------------------------------------------------------
// Kernel 3: reduce 528 partial slots -> scalar f32.
// square_sum_l = N^2 exactly, so out = s1 / (N * sqrt(s2)).
// ---------------------------------------------------------------------------
__global__ __launch_bounds__(256) void finalize_kernel(const double* __restrict__ part1,
                                                       const double* __restrict__ part2,
                                                       float* __restrict__ out)
{
    __shared__ double r1[256], r2[256];
    const int tid = threadIdx.x;
    double a = 0.0, b = 0.0;
    #pragma unroll
    for (int u = 0; u < 3; ++u) {
        const int s = tid + u*256;
        if (s < NTRI) { a += part1[s]; b += part2[s]; }
    }
    r1[tid] = a; r2[tid] = b; __syncthreads();
    for (int off = 128; off; off >>= 1) {
        if (tid < off) { r1[tid] += r1[tid+off]; r2[tid] += r2[tid+off]; }
        __syncthreads();
    }
    if (tid == 0) out[0] = (float)(r1[0] / (sqrt(r2[0]) * (double)NSAMP));
}

// ---------------------------------------------------------------------------
extern "C" void kernel_launch(void* const* d_in, const int* in_sizes, int n_in,
                              void* d_out, int out_size, void* d_ws, size_t ws_size,
                              hipStream_t stream)
{
    const float* data   = (const float*)d_in[0]; // (2048,12) f32
    const int*   labels = (const int*)d_in[1];   // (2048,)   i32
    const float* params = (const float*)d_in[2]; // (3,12)    f32

    double* part1 = (double*)d_ws;                                   // 528 doubles
    double* part2 = part1 + NTRI;                                    // 528 doubles
    unsigned short* psi_hi = (unsigned short*)((char*)d_ws + 16384); // 16 MiB
    unsigned short* psi_lo = psi_hi + (size_t)NSAMP * DIM;           // 16 MiB

    sim_kernel<<<NSAMP, 256, 0, stream>>>(data, params, psi_hi, psi_lo);
    gram_kernel<<<NTRI, 256, 0, stream>>>(psi_hi, psi_lo, labels, part1, part2);
    finalize_kernel<<<1, 256, 0, stream>>>(part1, part2, (float*)d_out);
}

// Round 6
// 237.209 us; speedup vs baseline: 2.0088x; 2.0088x over previous
//
#include <hip/hip_runtime.h>
#include <math.h>

#define NQ    12
#define DIM   4096        // 2^NQ
#define K_EXT 8192        // [hi | lo] extended row
#define NSAMP 2048
#define NLAY  3
#define NT    32          // 2048/64 tiles per dimension
#define NTRI  528         // NT*(NT+1)/2 triangular blocks
#define BK    64
#define LDK   72          // LDS row stride (ushort); 144 B, 16B-aligned rows

typedef __attribute__((ext_vector_type(8)))  short bf16x8;   // 8 bf16 = 4 VGPRs
typedef __attribute__((ext_vector_type(16))) float floatx16; // MFMA 32x32 acc

__device__ __forceinline__ unsigned short f32_to_bf16(float x) {
    unsigned u = __builtin_bit_cast(unsigned, x);
    u += 0x7FFFu + ((u >> 16) & 1u);            // round-to-nearest-even
    return (unsigned short)(u >> 16);
}
__device__ __forceinline__ float bf16_to_f32(unsigned short h) {
    unsigned u = (unsigned)h << 16;
    return __builtin_bit_cast(float, u);
}

// ---------------------------------------------------------------------------
// Kernel 1: 12-qubit circuit per sample, state in LDS.  Emits the split
// representation psi = hi + lo as ONE extended bf16 row: [hi(4096) | lo(4096)].
// Then psi_ext . psi_ext^T = hi.hi + hi.lo + lo.hi + lo.lo = exact product.
// ---------------------------------------------------------------------------
__global__ __launch_bounds__(256) void sim_kernel(const float* __restrict__ data,
                                                  const float* __restrict__ params,
                                                  unsigned short* __restrict__ pe)
{
    __shared__ float st[DIM];
    __shared__ float cs[NLAY*NQ], sn[NLAY*NQ];
    const int tid = threadIdx.x;
    const int smp = blockIdx.x;

    if (tid < NLAY*NQ) {
        const int q = tid % NQ;
        const float th = 0.5f * (params[tid] + data[smp*NQ + q]);
        cs[tid] = cosf(th);
        sn[tid] = sinf(th);
    }
    #pragma unroll
    for (int u = 0; u < DIM/256; ++u) st[tid + u*256] = 0.0f;
    if (tid == 0) st[0] = 1.0f;
    __syncthreads();

    for (int l = 0; l < NLAY; ++l) {
        for (int q = 0; q < NQ; ++q) {
            const float c = cs[l*NQ + q], s = sn[l*NQ + q];
            const int m = 1 << q;
            #pragma unroll
            for (int u = 0; u < DIM/2/256; ++u) {
                const int p  = tid + u*256;
                const int i0 = ((p & ~(m-1)) << 1) | (p & (m-1));
                const int i1 = i0 | m;
                const float a0 = st[i0], a1 = st[i1];
                st[i0] = c*a0 - s*a1;
                st[i1] = s*a0 + c*a1;
            }
            __syncthreads();
        }
        #pragma unroll
        for (int u = 0; u < DIM/256; ++u) {
            const int i = tid + u*256;
            const int y = (i >> 1) | ((i & 1) << (NQ-1));
            if (__popc(i & y) & 1) st[i] = -st[i];
        }
        __syncthreads();
    }
    // 4 amps/thread/iter -> ushort4 stores (8 B/lane, coalesced)
    const size_t base = (size_t)smp * K_EXT;
    #pragma unroll
    for (int u = 0; u < DIM/1024; ++u) {
        const int i = (tid + u*256) * 4;
        ushort4 vh, vl;
        {
            const float x0 = st[i],   x1 = st[i+1], x2 = st[i+2], x3 = st[i+3];
            const unsigned short h0 = f32_to_bf16(x0), h1 = f32_to_bf16(x1);
            const unsigned short h2 = f32_to_bf16(x2), h3 = f32_to_bf16(x3);
            vh.x = h0; vh.y = h1; vh.z = h2; vh.w = h3;
            vl.x = f32_to_bf16(x0 - bf16_to_f32(h0));
            vl.y = f32_to_bf16(x1 - bf16_to_f32(h1));
            vl.z = f32_to_bf16(x2 - bf16_to_f32(h2));
            vl.w = f32_to_bf16(x3 - bf16_to_f32(h3));
        }
        *(ushort4*)&pe[base + i]        = vh;
        *(ushort4*)&pe[base + DIM + i]  = vl;
    }
}

// ---------------------------------------------------------------------------
// Kernel 2: bf16 Gram over K_EXT=8192 + fused reduction, triangular grid.
// 64x64 tile/block, 4 waves K-split within each BK=64 stage, 2-stage register
// prefetch pipeline (loads issue ~2 stages ahead of their LDS write).
// ---------------------------------------------------------------------------
__global__ __launch_bounds__(256) void gram_kernel(const unsigned short* __restrict__ pe,
                                                   const int* __restrict__ labels,
                                                   double* __restrict__ part1,
                                                   double* __restrict__ part2)
{
    __shared__ __align__(16) unsigned short stage[2*64*LDK];   // A | B, 18 KiB
    __shared__ float la[64], lb[64];

    unsigned short* A = stage;
    unsigned short* B = stage + 64*LDK;
    float*  Gt  = (float*)stage;       // alias: live after main loop (64 x 66)
    double* red = (double*)stage;      // alias: live after Gt reads complete

    const int tid = threadIdx.x;
    const int bid = blockIdx.x;

    // triangular index -> (bi,bj), bj >= bi
    int bi = (int)((65.0 - sqrt(65.0*65.0 - 8.0*(double)bid)) * 0.5);
    int start = bi*(65-bi)/2;
    while (bid < start)              { --bi; start = bi*(65-bi)/2; }
    while (bid >= start + (NT - bi)) { start += NT - bi; ++bi; }
    const int bj = bi + (bid - start);

    if (tid < 64)       la[tid]      = 2.0f*(float)labels[bi*64 + tid]      - 1.0f;
    else if (tid < 128) lb[tid - 64] = 2.0f*(float)labels[bj*64 + tid - 64] - 1.0f;

    const int wave = tid >> 6, lane = tid & 63;
    const int mrow = lane & 31;
    const int kgrp = (lane >> 5) * 8;   // A/B layout: lane holds M[lane&31][(lane>>5)*8+j]
    const int ro   = wave*16 + kgrp;    // this wave's k-offset within the stage

    floatx16 acc00, acc01, acc10, acc11;
    #pragma unroll
    for (int i = 0; i < 16; ++i) { acc00[i]=0.f; acc01[i]=0.f; acc10[i]=0.f; acc11[i]=0.f; }

    // staging map: thread -> row sr (0..63), 16B chunks at c0 and c0+32 (ushort)
    const int sr = tid >> 2;
    const int c0 = (tid & 3) * 8;
    const unsigned short* gA = pe + ((size_t)bi*64 + sr) * K_EXT + c0;
    const unsigned short* gB = pe + ((size_t)bj*64 + sr) * K_EXT + c0;
    unsigned short* sA = &A[sr*LDK + c0];
    unsigned short* sB = &B[sr*LDK + c0];

    // prologue: stage 0 -> regs r*, stage 1 -> regs s*
    uint4 ra0 = *(const uint4*)(gA +  0), ra1 = *(const uint4*)(gA + 32);
    uint4 rb0 = *(const uint4*)(gB +  0), rb1 = *(const uint4*)(gB + 32);
    uint4 sa0 = *(const uint4*)(gA + 64), sa1 = *(const uint4*)(gA + 96);
    uint4 sb0 = *(const uint4*)(gB + 64), sb1 = *(const uint4*)(gB + 96);

    for (int kk = 0; kk < K_EXT; kk += 2*BK) {
        // ---- phase A: stage kk ----
        __syncthreads();                       // prev readers done
        *(uint4*)(sA +  0) = ra0; *(uint4*)(sA + 32) = ra1;
        *(uint4*)(sB +  0) = rb0; *(uint4*)(sB + 32) = rb1;
        __syncthreads();
        if (kk + 128 < K_EXT) {                // prefetch stage kk+128
            ra0 = *(const uint4*)(gA + kk + 128); ra1 = *(const uint4*)(gA + kk + 160);
            rb0 = *(const uint4*)(gB + kk + 128); rb1 = *(const uint4*)(gB + kk + 160);
        }
        {
            const bf16x8 av0 = *(const bf16x8*)&A[(mrow     )*LDK + ro];
            const bf16x8 av1 = *(const bf16x8*)&A[(mrow + 32)*LDK + ro];
            const bf16x8 bv0 = *(const bf16x8*)&B[(mrow     )*LDK + ro];
            const bf16x8 bv1 = *(const bf16x8*)&B[(mrow + 32)*LDK + ro];
            acc00 = __builtin_amdgcn_mfma_f32_32x32x16_bf16(av0, bv0, acc00, 0, 0, 0);
            acc01 = __builtin_amdgcn_mfma_f32_32x32x16_bf16(av0, bv1, acc01, 0, 0, 0);
            acc10 = __builtin_amdgcn_mfma_f32_32x32x16_bf16(av1, bv0, acc10, 0, 0, 0);
            acc11 = __builtin_amdgcn_mfma_f32_32x32x16_bf16(av1, bv1, acc11, 0, 0, 0);
        }
        // ---- phase B: stage kk+64 ----
        __syncthreads();
        *(uint4*)(sA +  0) = sa0; *(uint4*)(sA + 32) = sa1;
        *(uint4*)(sB +  0) = sb0; *(uint4*)(sB + 32) = sb1;
        __syncthreads();
        if (kk + 192 < K_EXT) {                // prefetch stage kk+192
            sa0 = *(const uint4*)(gA + kk + 192); sa1 = *(const uint4*)(gA + kk + 224);
            sb0 = *(const uint4*)(gB + kk + 192); sb1 = *(const uint4*)(gB + kk + 224);
        }
        {
            const bf16x8 av0 = *(const bf16x8*)&A[(mrow     )*LDK + ro];
            const bf16x8 av1 = *(const bf16x8*)&A[(mrow + 32)*LDK + ro];
            const bf16x8 bv0 = *(const bf16x8*)&B[(mrow     )*LDK + ro];
            const bf16x8 bv1 = *(const bf16x8*)&B[(mrow + 32)*LDK + ro];
            acc00 = __builtin_amdgcn_mfma_f32_32x32x16_bf16(av0, bv0, acc00, 0, 0, 0);
            acc01 = __builtin_amdgcn_mfma_f32_32x32x16_bf16(av0, bv1, acc01, 0, 0, 0);
            acc10 = __builtin_amdgcn_mfma_f32_32x32x16_bf16(av1, bv0, acc10, 0, 0, 0);
            acc11 = __builtin_amdgcn_mfma_f32_32x32x16_bf16(av1, bv1, acc11, 0, 0, 0);
        }
    }

    __syncthreads();   // all staging reads done; stage memory reusable as Gt

    // Sum the 4 wave K-partials into Gt.  C/D layout (m74/m101):
    // row_local = (reg&3) + 8*(reg>>2) + 4*(lane>>5), col_local = lane&31.
    const int crow = (lane >> 5) * 4;
    const int ccol = lane & 31;
    for (int w = 0; w < 4; ++w) {
        if (wave == w) {
            #pragma unroll
            for (int r = 0; r < 16; ++r) {
                const int rl = (r & 3) + 8*(r >> 2) + crow;
                if (w == 0) {
                    Gt[(rl     )*66 + ccol     ] = acc00[r];
                    Gt[(rl     )*66 + ccol + 32] = acc01[r];
                    Gt[(rl + 32)*66 + ccol     ] = acc10[r];
                    Gt[(rl + 32)*66 + ccol + 32] = acc11[r];
                } else {
                    Gt[(rl     )*66 + ccol     ] += acc00[r];
                    Gt[(rl     )*66 + ccol + 32] += acc01[r];
                    Gt[(rl + 32)*66 + ccol     ] += acc10[r];
                    Gt[(rl + 32)*66 + ccol + 32] += acc11[r];
                }
            }
        }
        __syncthreads();
    }

    // Reduce: s1 += w*l_i*l_j*G^2, s2 += w*G^4 (w = 2 above diag, 1 on, 0 below)
    double s1 = 0.0, s2 = 0.0;
    #pragma unroll
    for (int u = 0; u < 16; ++u) {
        const int e   = u*256 + tid;
        const int row = e >> 6, col = e & 63;
        const float g = Gt[row*66 + col];
        const float w = (bi < bj) ? 2.0f : ((row < col) ? 2.0f : ((row == col) ? 1.0f : 0.0f));
        const float g2 = g * g;
        s1 += (double)(w * la[row] * lb[col] * g2);
        const double d = (double)g2;
        s2 += (double)w * d * d;
    }
    __syncthreads();   // Gt reads done before red alias is written

    red[tid] = s1; __syncthreads();
    for (int off = 128; off; off >>= 1) { if (tid < off) red[tid] += red[tid+off]; __syncthreads(); }
    if (tid == 0) part1[bid] = red[0];
    __syncthreads();
    red[tid] = s2; __syncthreads();
    for (int off = 128; off; off >>= 1) { if (tid < off) red[tid] += red[tid+off]; __syncthreads(); }
    if (tid == 0) part2[bid] = red[0];
}

// ---------------------------------------------------------------------------
// Kernel 3: reduce 528 partial slots -> scalar f32.
// square_sum_l = N^2 exactly, so out = s1 / (N * sqrt(s2)).
// ---------------------------------------------------------------------------
__global__ __launch_bounds__(256) void finalize_kernel(const double* __restrict__ part1,
                                                       const double* __restrict__ part2,
                                                       float* __restrict__ out)
{
    __shared__ double r1[256], r2[256];
    const int tid = threadIdx.x;
    double a = 0.0, b = 0.0;
    #pragma unroll
    for (int u = 0; u < 3; ++u) {
        const int s = tid + u*256;
        if (s < NTRI) { a += part1[s]; b += part2[s]; }
    }
    r1[tid] = a; r2[tid] = b; __syncthreads();
    for (int off = 128; off; off >>= 1) {
        if (tid < off) { r1[tid] += r1[tid+off]; r2[tid] += r2[tid+off]; }
        __syncthreads();
    }
    if (tid == 0) out[0] = (float)(r1[0] / (sqrt(r2[0]) * (double)NSAMP));
}

// ---------------------------------------------------------------------------
extern "C" void kernel_launch(void* const* d_in, const int* in_sizes, int n_in,
                              void* d_out, int out_size, void* d_ws, size_t ws_size,
                              hipStream_t stream)
{
    const float* data   = (const float*)d_in[0]; // (2048,12) f32
    const int*   labels = (const int*)d_in[1];   // (2048,)   i32
    const float* params = (const float*)d_in[2]; // (3,12)    f32

    double* part1 = (double*)d_ws;                                    // 528 doubles
    double* part2 = part1 + NTRI;                                     // 528 doubles
    unsigned short* psi_ext = (unsigned short*)((char*)d_ws + 16384); // 2048x8192 bf16 = 32 MiB

    sim_kernel<<<NSAMP, 256, 0, stream>>>(data, params, psi_ext);
    gram_kernel<<<NTRI, 256, 0, stream>>>(psi_ext, labels, part1, part2);
    finalize_kernel<<<1, 256, 0, stream>>>(part1, part2, (float*)d_out);
}